// Round 3
// baseline (151.324 us; speedup 1.0000x reference)
//
#include <hip/hip_runtime.h>
#include <hip/hip_bf16.h>

// ---------- constants (problem is fully static) ----------
#define NQ  13294
#define NV  13294
#define BQ  26588          // B * NQ

typedef __attribute__((ext_vector_type(8))) short short8;
typedef __attribute__((ext_vector_type(4))) float f32x4;

static __device__ __forceinline__ ushort f2bf(float f) {
    unsigned int x = __float_as_uint(f);
    unsigned int r = (x + 0x7fffu + ((x >> 16) & 1u)) >> 16;
    return (ushort)r;
}
static __device__ __forceinline__ uint cvtpk(float a, float b) {
    uint r;
    asm("v_cvt_pk_bf16_f32 %0, %1, %2" : "=v"(r) : "v"(a), "v"(b));
    return r;   // lo16 = bf16(a), hi16 = bf16(b)
}

// ---------- weight prep: transpose to [N][K] bf16, concat biases ----------
__global__ __launch_bounds__(256) void prep_weights(
    const float* __restrict__ Wv, const float* __restrict__ Wo,
    const float* __restrict__ Wa, const float* __restrict__ Wu,
    const float* __restrict__ bo, const float* __restrict__ ba,
    ushort* __restrict__ tWv, ushort* __restrict__ tWoa,
    ushort* __restrict__ tWu, float* __restrict__ boa) {
    int i = blockIdx.x * 256 + threadIdx.x;
    if (i < 65536) {                       // W_val^T [256][256]
        int n = i >> 8, k = i & 255;
        tWv[i] = f2bf(Wv[k * 256 + n]);
    } else if (i < 65536 + 98304) {        // [W_off | W_attn]^T [384][256]
        int j = i - 65536;
        int n = j >> 8, k = j & 255;
        tWoa[j] = f2bf(n < 256 ? Wo[k * 256 + n] : Wa[k * 128 + (n - 256)]);
    } else if (i < 229376) {               // W_out^T [256][256]
        int j = i - 163840;
        int n = j >> 8, k = j & 255;
        tWu[j] = f2bf(Wu[k * 256 + n]);
    } else if (i < 229760) {               // bias concat [384]
        int j = i - 229376;
        boa[j] = j < 256 ? bo[j] : ba[j - 256];
    }
}

// ---------- bf16 MFMA GEMM core: C[M,N] = A[M,256] * Bt[N,256]^T + bias ----
// Tile 128x128, BK=64, 4 waves (2x2), wave tile 64x64 = 4x4 frags 16x16x32.
// LDS [128 rows][64 k] bf16, XOR-swizzle: byte ^= ((row&7)<<4)  (conflict-free)
// Reg-prefetch of next K-tile overlaps MFMA.
template<int AF32>
static __device__ __forceinline__ void gemm_core(
    const void* __restrict__ Aptr, const ushort* __restrict__ Bt,
    const float* __restrict__ bias, void* __restrict__ Cout,
    int M, int N, int out_bf16, int mblk, int nblk,
    ushort* sA, ushort* sB) {
    const int tid = threadIdx.x;
    const int wid = tid >> 6, lane = tid & 63;
    const int row0 = mblk * 128, col0 = nblk * 128;
    const int wr = (wid >> 1) * 64, wc = (wid & 1) * 64;

    f32x4 acc[4][4];
#pragma unroll
    for (int m = 0; m < 4; ++m)
#pragma unroll
        for (int n = 0; n < 4; ++n) acc[m][n] = (f32x4){0.f, 0.f, 0.f, 0.f};

    // staging indexing
    const int arow = tid >> 4;            // A f32: +16 per j (8 loads)
    const int akf  = (tid & 15) * 4;      // f32 k-col
    const int brow = tid >> 3;            // bf16: +32 per j (4 loads)
    const int bk   = (tid & 7) * 8;       // ushort k-col

    float4 raf[8];
    uint4  rab[4];
    uint4  rb[4];

    auto LOAD = [&](int kk) {
        if (AF32) {
            const float* Af = (const float*)Aptr;
#pragma unroll
            for (int j = 0; j < 8; ++j) {
                int gr = row0 + arow + j * 16; gr = gr < M ? gr : M - 1;
                raf[j] = *(const float4*)(Af + (size_t)gr * 256 + kk + akf);
            }
        } else {
            const ushort* Ab = (const ushort*)Aptr;
#pragma unroll
            for (int j = 0; j < 4; ++j) {
                int gr = row0 + brow + j * 32; gr = gr < M ? gr : M - 1;
                rab[j] = *(const uint4*)(Ab + (size_t)gr * 256 + kk + bk);
            }
        }
#pragma unroll
        for (int j = 0; j < 4; ++j) {
            int gc = col0 + brow + j * 32;
            rb[j] = *(const uint4*)(Bt + (size_t)gc * 256 + kk + bk);
        }
    };
    auto STORE = [&]() {
        if (AF32) {
#pragma unroll
            for (int j = 0; j < 8; ++j) {
                int r = arow + j * 16;
                uint2 w;
                w.x = cvtpk(raf[j].x, raf[j].y);
                w.y = cvtpk(raf[j].z, raf[j].w);
                *(uint2*)((char*)sA + r * 128 + ((akf * 2) ^ ((r & 7) << 4))) = w;
            }
        } else {
#pragma unroll
            for (int j = 0; j < 4; ++j) {
                int r = brow + j * 32;
                *(uint4*)((char*)sA + r * 128 + ((bk * 2) ^ ((r & 7) << 4))) = rab[j];
            }
        }
#pragma unroll
        for (int j = 0; j < 4; ++j) {
            int r = brow + j * 32;
            *(uint4*)((char*)sB + r * 128 + ((bk * 2) ^ ((r & 7) << 4))) = rb[j];
        }
    };

    LOAD(0);
#pragma unroll
    for (int step = 0; step < 4; ++step) {
        if (step) __syncthreads();        // all frag reads of prev step done
        STORE();
        __syncthreads();
        if (step < 3) LOAD((step + 1) * 64);   // overlaps MFMA below
        const int rbase = lane & 15;
        const int swz = (lane & 7) << 4;
#pragma unroll
        for (int ks = 0; ks < 2; ++ks) {
            short8 a[4], b[4];
            const int koff = (ks * 64 + (lane >> 4) * 16) ^ swz;
#pragma unroll
            for (int m = 0; m < 4; ++m)
                a[m] = *(const short8*)((char*)sA + (wr + m * 16 + rbase) * 128 + koff);
#pragma unroll
            for (int n = 0; n < 4; ++n)
                b[n] = *(const short8*)((char*)sB + (wc + n * 16 + rbase) * 128 + koff);
#pragma unroll
            for (int m = 0; m < 4; ++m)
#pragma unroll
                for (int n = 0; n < 4; ++n)
                    acc[m][n] = __builtin_amdgcn_mfma_f32_16x16x32_bf16(a[m], b[n], acc[m][n], 0, 0, 0);
        }
    }

    // epilogue: lane holds C[row=(lane>>4)*4+j][col=lane&15] per fragment
    const int lr = (lane >> 4) * 4;
    const int lc = lane & 15;
#pragma unroll
    for (int m = 0; m < 4; ++m) {
#pragma unroll
        for (int n = 0; n < 4; ++n) {
            int gcol = col0 + wc + n * 16 + lc;
            float bv = bias[gcol];
#pragma unroll
            for (int j = 0; j < 4; ++j) {
                int grow = row0 + wr + m * 16 + lr + j;
                if (grow < M) {
                    float vv = acc[m][n][j] + bv;
                    if (out_bf16)
                        ((ushort*)Cout)[(size_t)grow * N + gcol] = f2bf(vv);
                    else
                        ((float*)Cout)[(size_t)grow * N + gcol] = vv;
                }
            }
        }
    }
}

// merged GEMM1 (value->vproj bf16, y=0..1) + GEMM2 (query->offattn f32, y=2..4)
__global__ __launch_bounds__(256) void gemm_fused(
    const float* __restrict__ value, const float* __restrict__ query,
    const ushort* __restrict__ tWv, const ushort* __restrict__ tWoa,
    const float* __restrict__ bval, const float* __restrict__ boa,
    ushort* __restrict__ vproj, float* __restrict__ offattn) {
    __shared__ ushort sA[128 * 64];
    __shared__ ushort sB[128 * 64];
    const bool g1 = blockIdx.y < 2;
    gemm_core<1>(g1 ? (const void*)value : (const void*)query,
                 g1 ? tWv : tWoa, g1 ? bval : boa,
                 g1 ? (void*)vproj : (void*)offattn,
                 BQ, g1 ? 256 : 384, g1 ? 1 : 0,
                 blockIdx.x, g1 ? blockIdx.y : blockIdx.y - 2, sA, sB);
}

__global__ __launch_bounds__(256) void gemm_out(
    const ushort* __restrict__ outacc, const ushort* __restrict__ tWu,
    const float* __restrict__ bout, float* __restrict__ dout) {
    __shared__ ushort sA[128 * 64];
    __shared__ ushort sB[128 * 64];
    gemm_core<0>(outacc, tWu, bout, dout, BQ, 256, 0, blockIdx.x, blockIdx.y, sA, sB);
}

// ---------- softmax + bilinear sampling + head-weighted accumulation ----------
// One WAVE per (b,q); 4 queries/block. Lane = h*8 + s2*4 + d4.
// Table: per slot u (0..127) a 32B entry {(i0,w0,i1,w1),(i2,w2,i3,w3)} with the
// two 16B halves XOR-swapped by bit2(u) so both table reads are conflict-free.
// Gather loop: 2-deep ping-pong software pipeline, 8 dwordx4 gathers in flight.
__global__ __launch_bounds__(256) void msda_sample(
    const float* __restrict__ offattn,   // [BQ, 384] : 256 offsets + 128 logits
    const float* __restrict__ refp,      // [B, NQ, 4, 2]
    const ushort* __restrict__ v,        // bf16 [B, NV, 256] (col = h*32+d)
    ushort* __restrict__ out_acc) {      // bf16 [BQ, 256]
    __shared__ int4 s_tbl[4][256];       // 4KB per query

    const int tid = threadIdx.x;
    const int qi = tid >> 6;
    const int lane = tid & 63;
    const int bq = blockIdx.x * 4 + qi;  // 26588 = 4 * 6647 exact
    const int b = bq / NQ;
    const int q = bq - b * NQ;

    // ---- prep: each lane owns table entries t0=2*lane, t0+1 ----
    const float* oa = offattn + (size_t)bq * 384;
    const int t0 = lane * 2;
    float2 lg = *(const float2*)(oa + 256 + t0);
    float m = fmaxf(lg.x, lg.y);
    m = fmaxf(m, __shfl_xor(m, 1));
    m = fmaxf(m, __shfl_xor(m, 2));
    m = fmaxf(m, __shfl_xor(m, 4));      // max over the head's 16 logits
    float e0 = __expf(lg.x - m), e1 = __expf(lg.y - m);
    float ssum = e0 + e1;
    ssum += __shfl_xor(ssum, 1);
    ssum += __shfl_xor(ssum, 2);
    ssum += __shfl_xor(ssum, 4);
    float inv = 1.f / ssum;

    float4 off4 = *(const float4*)(oa + 2 * t0);  // (ox0,oy0,ox1,oy1)
    const int l = (t0 >> 2) & 3;
    const int   Wi = (l == 0) ? 100 : (l == 1) ? 50 : (l == 2) ? 25 : 13;
    const int   st = (l == 0) ? 0 : (l == 1) ? 10000 : (l == 2) ? 12500 : 13125;
    const float Wf = (float)Wi;
    float rx = refp[(((size_t)b * NQ + q) * 4 + l) * 2 + 0];
    float ry = refp[(((size_t)b * NQ + q) * 4 + l) * 2 + 1];

    char* tblw = (char*)&s_tbl[qi][0];
#pragma unroll
    for (int j = 0; j < 2; ++j) {
        int t = t0 + j;
        float e = (j ? e1 : e0) * inv;
        float ox = j ? off4.z : off4.x;
        float oy = j ? off4.w : off4.y;
        float x = fmaf(rx, Wf, ox) - 0.5f;
        float y = fmaf(ry, Wf, oy) - 0.5f;
        float x0f = floorf(x), y0f = floorf(y);
        float fx = x - x0f, fy = y - y0f;
        int x0 = (int)x0f, y0 = (int)y0f;
        float wx[2] = {1.f - fx, fx}, wy[2] = {1.f - fy, fy};
        int   iw[4]; float wv[4];
#pragma unroll
        for (int c = 0; c < 4; ++c) {
            int dx = c & 1, dy = c >> 1;
            int xi = x0 + dx, yi = y0 + dy;
            bool valid = (xi >= 0) & (xi < Wi) & (yi >= 0) & (yi < Wi);
            int cx = min(max(xi, 0), Wi - 1);
            int cy = min(max(yi, 0), Wi - 1);
            iw[c] = st + cy * Wi + cx;
            wv[c] = valid ? e * wx[dx] * wy[dy] : 0.f;
        }
        int u = ((t & 7) << 4) | (t >> 3);
        int su = (u & 4) ? 16 : 0;
        *(int4*)(tblw + u * 32 + su)        = make_int4(iw[0], __float_as_int(wv[0]), iw[1], __float_as_int(wv[1]));
        *(int4*)(tblw + u * 32 + (16 ^ su)) = make_int4(iw[2], __float_as_int(wv[2]), iw[3], __float_as_int(wv[3]));
    }
    __syncthreads();

    // ---- gather: pipelined, lane (h, s2, d4) accumulates 8 channels ----
    const int h  = lane >> 3;
    const int s2 = (lane >> 2) & 1;
    const int d4 = lane & 3;
    const char* tbl = (const char*)&s_tbl[qi][0] + (h * 2 + s2) * 32;
    const int sa = ((h >> 1) & 1) << 4;
    const char* tA = tbl + sa;
    const char* tB = tbl + (16 ^ sa);
    const ushort* vB = v + (size_t)b * NV * 256 + h * 32 + d4 * 8;

    float acc[8] = {0.f, 0.f, 0.f, 0.f, 0.f, 0.f, 0.f, 0.f};
    int4 pa, pb, qa, qb;
    uint4 g[4], f[4];

    auto TB = [&](int ss, int4& A_, int4& B_) {
        A_ = *(const int4*)(tA + ss * 512);
        B_ = *(const int4*)(tB + ss * 512);
    };
    auto GD = [&](const int4& A_, const int4& B_, uint4* G) {
        G[0] = *(const uint4*)(vB + (size_t)(uint)A_.x * 256);
        G[1] = *(const uint4*)(vB + (size_t)(uint)A_.z * 256);
        G[2] = *(const uint4*)(vB + (size_t)(uint)B_.x * 256);
        G[3] = *(const uint4*)(vB + (size_t)(uint)B_.z * 256);
    };
    auto FM = [&](const int4& A_, const int4& B_, const uint4* G) {
#pragma unroll
        for (int c = 0; c < 4; ++c) {
            float w = __int_as_float(c == 0 ? A_.y : c == 1 ? A_.w : c == 2 ? B_.y : B_.w);
            uint4 u4 = G[c];
            acc[0] = fmaf(__uint_as_float(u4.x << 16), w, acc[0]);
            acc[1] = fmaf(__uint_as_float(u4.x & 0xffff0000u), w, acc[1]);
            acc[2] = fmaf(__uint_as_float(u4.y << 16), w, acc[2]);
            acc[3] = fmaf(__uint_as_float(u4.y & 0xffff0000u), w, acc[3]);
            acc[4] = fmaf(__uint_as_float(u4.z << 16), w, acc[4]);
            acc[5] = fmaf(__uint_as_float(u4.z & 0xffff0000u), w, acc[5]);
            acc[6] = fmaf(__uint_as_float(u4.w << 16), w, acc[6]);
            acc[7] = fmaf(__uint_as_float(u4.w & 0xffff0000u), w, acc[7]);
        }
    };

    TB(0, pa, pb); GD(pa, pb, g);
    TB(1, qa, qb); GD(qa, qb, f);
    FM(pa, pb, g);
    TB(2, pa, pb); GD(pa, pb, g);
    FM(qa, qb, f);
    TB(3, qa, qb); GD(qa, qb, f);
    FM(pa, pb, g);
    TB(4, pa, pb); GD(pa, pb, g);
    FM(qa, qb, f);
    TB(5, qa, qb); GD(qa, qb, f);
    FM(pa, pb, g);
    TB(6, pa, pb); GD(pa, pb, g);
    FM(qa, qb, f);
    TB(7, qa, qb); GD(qa, qb, f);
    FM(pa, pb, g);
    FM(qa, qb, f);

#pragma unroll
    for (int i = 0; i < 8; ++i) acc[i] += __shfl_xor(acc[i], 4);   // reduce over s2
    if (s2 == 0) {
        uint4 o;
        o.x = cvtpk(acc[0], acc[1]);
        o.y = cvtpk(acc[2], acc[3]);
        o.z = cvtpk(acc[4], acc[5]);
        o.w = cvtpk(acc[6], acc[7]);
        *(uint4*)(out_acc + (size_t)bq * 256 + h * 32 + d4 * 8) = o;
    }
}

// ---------- launch ----------
extern "C" void kernel_launch(void* const* d_in, const int* in_sizes, int n_in,
                              void* d_out, int out_size, void* d_ws, size_t ws_size,
                              hipStream_t stream) {
    const float* query  = (const float*)d_in[0];
    const float* value  = (const float*)d_in[1];
    const float* refp   = (const float*)d_in[2];
    const float* W_off  = (const float*)d_in[5];
    const float* b_off  = (const float*)d_in[6];
    const float* W_attn = (const float*)d_in[7];
    const float* b_attn = (const float*)d_in[8];
    const float* W_val  = (const float*)d_in[9];
    const float* b_val  = (const float*)d_in[10];
    const float* W_out  = (const float*)d_in[11];
    const float* b_out  = (const float*)d_in[12];

    const size_t ROWB = (size_t)BQ * 256 * 2;   // bytes of one bf16 [BQ,256] buffer
    char* ws = (char*)d_ws;
    ushort* vproj   = (ushort*)(ws);
    ushort* outacc  = (ushort*)(ws + ROWB);
    float*  offattn = (float*)(ws + 2 * ROWB);                    // [BQ,384] fp32
    char*   wbase   = ws + 2 * ROWB + (size_t)BQ * 384 * 4;
    ushort* tWv  = (ushort*)(wbase);
    ushort* tWoa = tWv + 65536;
    ushort* tWu  = tWoa + 98304;
    float*  boa  = (float*)(tWu + 65536);

    prep_weights<<<(229760 + 255) / 256, 256, 0, stream>>>(
        W_val, W_off, W_attn, W_out, b_off, b_attn, tWv, tWoa, tWu, boa);

    gemm_fused<<<dim3(208, 5), 256, 0, stream>>>(
        value, query, tWv, tWoa, b_val, boa, vproj, offattn);

    msda_sample<<<BQ / 4, 256, 0, stream>>>(offattn, refp, vproj, outacc);

    gemm_out<<<dim3(208, 2), 256, 0, stream>>>(outacc, tWu, b_out, (float*)d_out);
}

// Round 4
// 107.853 us; speedup vs baseline: 1.4031x; 1.4031x over previous
//
#include <hip/hip_runtime.h>
#include <hip/hip_bf16.h>

// ---------- constants (problem is fully static) ----------
#define NQ  13294
#define NV  13294
#define BQ  26588          // B * NQ

typedef __attribute__((ext_vector_type(8))) short short8;
typedef __attribute__((ext_vector_type(4))) float f32x4;

static __device__ __forceinline__ ushort f2bf(float f) {
    unsigned int x = __float_as_uint(f);
    unsigned int r = (x + 0x7fffu + ((x >> 16) & 1u)) >> 16;
    return (ushort)r;
}
static __device__ __forceinline__ uint cvtpk_bf16(float a, float b) {
    uint r;
    asm("v_cvt_pk_bf16_f32 %0, %1, %2" : "=v"(r) : "v"(a), "v"(b));
    return r;   // lo16 = bf16(a), hi16 = bf16(b)
}
static __device__ __forceinline__ uint cvtpk_f16(float a, float b) {
    uint r;
    asm("v_cvt_pkrtz_f16_f32 %0, %1, %2" : "=v"(r) : "v"(a), "v"(b));
    return r;   // lo16 = f16(a), hi16 = f16(b)
}
static __device__ __forceinline__ float f16lo(uint u) {
    _Float16 h; ushort t = (ushort)(u & 0xffffu);
    __builtin_memcpy(&h, &t, 2); return (float)h;
}
static __device__ __forceinline__ float f16hi(uint u) {
    _Float16 h; ushort t = (ushort)(u >> 16);
    __builtin_memcpy(&h, &t, 2); return (float)h;
}

// ---------- weight prep: transpose to [N][K] bf16, concat biases ----------
__global__ __launch_bounds__(256) void prep_weights(
    const float* __restrict__ Wv, const float* __restrict__ Wo,
    const float* __restrict__ Wa, const float* __restrict__ Wu,
    const float* __restrict__ bo, const float* __restrict__ ba,
    ushort* __restrict__ tWv, ushort* __restrict__ tWoa,
    ushort* __restrict__ tWu, float* __restrict__ boa) {
    int i = blockIdx.x * 256 + threadIdx.x;
    if (i < 65536) {                       // W_val^T [256][256]
        int n = i >> 8, k = i & 255;
        tWv[i] = f2bf(Wv[k * 256 + n]);
    } else if (i < 65536 + 98304) {        // [W_off | W_attn]^T [384][256]
        int j = i - 65536;
        int n = j >> 8, k = j & 255;
        tWoa[j] = f2bf(n < 256 ? Wo[k * 256 + n] : Wa[k * 128 + (n - 256)]);
    } else if (i < 229376) {               // W_out^T [256][256]
        int j = i - 163840;
        int n = j >> 8, k = j & 255;
        tWu[j] = f2bf(Wu[k * 256 + n]);
    } else if (i < 229760) {               // bias concat [384]
        int j = i - 229376;
        boa[j] = j < 256 ? bo[j] : ba[j - 256];
    }
}

// ---------- bf16 MFMA GEMM core (round-2 proven structure) ----------
// Tile 128x128, BK=32, 4 waves (2x2), wave 64x64 = 4x4 frags of 16x16x32.
// out_mode: 0 = f32 [M,N];  2 = fp16 [M,N];  3 = bf16 scattered to
//           vproj_t[(b*8+h)*NV + pix][32] with h=col>>5, ch=col&31.
#define LDP 40   // padded LDS row (bf16 elems)

template<int AF32>
static __device__ __forceinline__ void gemm_core(
    const void* __restrict__ Aptr, const ushort* __restrict__ Bt,
    const float* __restrict__ bias, void* __restrict__ Cout,
    int M, int N, int out_mode, int mblk, int nblk,
    ushort* sA, ushort* sB) {
    const int tid = threadIdx.x;
    const int wid = tid >> 6;
    const int lane = tid & 63;
    const int row0 = mblk * 128;
    const int col0 = nblk * 128;
    const int wr = (wid >> 1) * 64;
    const int wc = (wid & 1) * 64;

    f32x4 acc[4][4];
#pragma unroll
    for (int m = 0; m < 4; ++m)
#pragma unroll
        for (int n = 0; n < 4; ++n) acc[m][n] = (f32x4){0.f, 0.f, 0.f, 0.f};

    for (int kk = 0; kk < 256; kk += 32) {
        __syncthreads();
#pragma unroll
        for (int it = 0; it < 2; ++it) {
            int chunk = tid + it * 256;       // 0..511
            int r = chunk >> 2;               // 0..127
            int seg = chunk & 3;              // 8-channel segment
            int gr = row0 + r; gr = gr < M ? gr : M - 1;
            uint4 wa;
            if (AF32) {
                const float* Af = (const float*)Aptr + (size_t)gr * 256 + kk + seg * 8;
                float4 f0 = *reinterpret_cast<const float4*>(Af);
                float4 f1 = *reinterpret_cast<const float4*>(Af + 4);
                wa.x = cvtpk_bf16(f0.x, f0.y);
                wa.y = cvtpk_bf16(f0.z, f0.w);
                wa.z = cvtpk_bf16(f1.x, f1.y);
                wa.w = cvtpk_bf16(f1.z, f1.w);
            } else {
                wa = *reinterpret_cast<const uint4*>((const ushort*)Aptr + (size_t)gr * 256 + kk + seg * 8);
            }
            *reinterpret_cast<uint4*>(&sA[r * LDP + seg * 8]) = wa;
            int gc = col0 + r;                // N multiple of 128
            uint4 vb4 = *reinterpret_cast<const uint4*>(Bt + (size_t)gc * 256 + kk + seg * 8);
            *reinterpret_cast<uint4*>(&sB[r * LDP + seg * 8]) = vb4;
        }
        __syncthreads();

        short8 a[4], b[4];
#pragma unroll
        for (int m = 0; m < 4; ++m)
            a[m] = *reinterpret_cast<const short8*>(&sA[(wr + m * 16 + (lane & 15)) * LDP + (lane >> 4) * 8]);
#pragma unroll
        for (int n = 0; n < 4; ++n)
            b[n] = *reinterpret_cast<const short8*>(&sB[(wc + n * 16 + (lane & 15)) * LDP + (lane >> 4) * 8]);
#pragma unroll
        for (int m = 0; m < 4; ++m)
#pragma unroll
            for (int n = 0; n < 4; ++n)
                acc[m][n] = __builtin_amdgcn_mfma_f32_16x16x32_bf16(a[m], b[n], acc[m][n], 0, 0, 0);
    }

    // epilogue: lane holds C[row=(lane>>4)*4+j][col=lane&15] per fragment
    const int lr = (lane >> 4) * 4;
    const int lc = lane & 15;
#pragma unroll
    for (int m = 0; m < 4; ++m) {
#pragma unroll
        for (int n = 0; n < 4; ++n) {
            int gcol = col0 + wc + n * 16 + lc;
            float bv = bias[gcol];
#pragma unroll
            for (int j = 0; j < 4; ++j) {
                int grow = row0 + wr + m * 16 + lr + j;
                if (grow < M) {
                    float vv = acc[m][n][j] + bv;
                    if (out_mode == 0) {
                        ((float*)Cout)[(size_t)grow * N + gcol] = vv;
                    } else if (out_mode == 2) {
                        ((ushort*)Cout)[(size_t)grow * N + gcol] = (ushort)(cvtpk_f16(vv, vv) & 0xffffu);
                    } else {   // mode 3: transposed value layout [b*8+h][pix][32]
                        int bb = grow >= NV;
                        int pix = grow - bb * NV;
                        int h = gcol >> 5, ch = gcol & 31;
                        ((ushort*)Cout)[(((size_t)(bb * 8 + h)) * NV + pix) * 32 + ch] = f2bf(vv);
                    }
                }
            }
        }
    }
}

// merged GEMM1 (value->vproj_t bf16, y=0..1) + GEMM2 (query->offattn fp16, y=2..4)
__global__ __launch_bounds__(256) void gemm_fused(
    const float* __restrict__ value, const float* __restrict__ query,
    const ushort* __restrict__ tWv, const ushort* __restrict__ tWoa,
    const float* __restrict__ bval, const float* __restrict__ boa,
    ushort* __restrict__ vproj_t, ushort* __restrict__ offattn) {
    __shared__ ushort sA[128 * LDP];
    __shared__ ushort sB[128 * LDP];
    const bool g1 = blockIdx.y < 2;
    gemm_core<1>(g1 ? (const void*)value : (const void*)query,
                 g1 ? tWv : tWoa, g1 ? bval : boa,
                 g1 ? (void*)vproj_t : (void*)offattn,
                 BQ, g1 ? 256 : 384, g1 ? 3 : 2,
                 blockIdx.x, g1 ? blockIdx.y : blockIdx.y - 2, sA, sB);
}

__global__ __launch_bounds__(256) void gemm_out(
    const ushort* __restrict__ outacc, const ushort* __restrict__ tWu,
    const float* __restrict__ bout, float* __restrict__ dout) {
    __shared__ ushort sA[128 * LDP];
    __shared__ ushort sB[128 * LDP];
    gemm_core<0>(outacc, tWu, bout, dout, BQ, 256, 0, blockIdx.x, blockIdx.y, sA, sB);
}

// ---------- softmax + bilinear sampling + head-weighted accumulation ----------
// One WAVE per (b,q); 4 queries/block. vproj_t layout [b*8+h][pix][32ch] bf16:
// the two x-corners of a sample are CONTIGUOUS 128B -> read row-pairs with
// 8 lanes/head (lane = h*8 + xbit*4 + channel-group). 2 loads per sample-row
// instead of 4 corner loads; both x-corners of each fetched line are consumed.
__global__ __launch_bounds__(256) void msda_sample(
    const ushort* __restrict__ offattn,  // fp16 [BQ, 384] : 256 offsets + 128 logits
    const float* __restrict__ refp,      // [B, NQ, 4, 2]
    const ushort* __restrict__ vt,       // bf16 [B*8][NV][32]
    ushort* __restrict__ out_acc) {      // bf16 [BQ, 256]
    __shared__ int4 s_tbl[4][128];       // entry e = h*16 + (s^h)  (bank-spread)

    const int tid = threadIdx.x;
    const int qi = tid >> 6;
    const int lane = tid & 63;
    const int bq = blockIdx.x * 4 + qi;  // 26588 = 4 * 6647 exact
    const int b = bq / NQ;
    const int q = bq - b * NQ;
    const int h = lane >> 3;

    // ---- prep: lane owns samples s0=2*(lane&7), s0+1 of head h ----
    const ushort* oa = offattn + (size_t)bq * 384;
    const int t0 = lane * 2;             // t = h*16 + s
    uint lgu = *reinterpret_cast<const uint*>(oa + 256 + t0);
    float lg0 = f16lo(lgu), lg1 = f16hi(lgu);
    float m = fmaxf(lg0, lg1);
    m = fmaxf(m, __shfl_xor(m, 1));
    m = fmaxf(m, __shfl_xor(m, 2));
    m = fmaxf(m, __shfl_xor(m, 4));      // max over the head's 16 logits
    float e0 = __expf(lg0 - m), e1 = __expf(lg1 - m);
    float ssum = e0 + e1;
    ssum += __shfl_xor(ssum, 1);
    ssum += __shfl_xor(ssum, 2);
    ssum += __shfl_xor(ssum, 4);
    float inv = 1.f / ssum;

    uint2 offu = *reinterpret_cast<const uint2*>(oa + 2 * t0);  // 4 fp16
    const int l = (t0 >> 2) & 3;
    const int   Wi = (l == 0) ? 100 : (l == 1) ? 50 : (l == 2) ? 25 : 13;
    const float Wf = (float)Wi;
    float rx = refp[(((size_t)b * NQ + q) * 4 + l) * 2 + 0];
    float ry = refp[(((size_t)b * NQ + q) * 4 + l) * 2 + 1];

#pragma unroll
    for (int j = 0; j < 2; ++j) {
        float e = (j ? e1 : e0) * inv;
        float ox = j ? f16lo(offu.y) : f16lo(offu.x);
        float oy = j ? f16hi(offu.y) : f16hi(offu.x);
        float x = fmaf(rx, Wf, ox) - 0.5f;
        float y = fmaf(ry, Wf, oy) - 0.5f;
        float x0f = floorf(x), y0f = floorf(y);
        float fx = x - x0f, fy = y - y0f;
        int x0 = (int)x0f, y0 = (int)y0f;
        float wa = (x0 >= 0 && x0 < Wi)         ? e * (1.f - fx) : 0.f;
        float wb = (x0 + 1 >= 0 && x0 + 1 < Wi) ? e * fx         : 0.f;
        float wy0 = (y0 >= 0 && y0 < Wi)         ? (1.f - fy) : 0.f;
        float wy1 = (y0 + 1 >= 0 && y0 + 1 < Wi) ? fy         : 0.f;
        int s = 2 * (lane & 7) + j;
        int4 ent;
        ent.x = (x0 & 0xffff) | (y0 << 16);
        ent.y = (int)cvtpk_f16(wa, wb);
        ent.z = (int)cvtpk_f16(wy0, wy1);
        ent.w = 0;
        s_tbl[qi][h * 16 + (s ^ h)] = ent;
    }
    __syncthreads();

    // ---- gather: lane = (h, xbit, cg); 2 row-reads per sample ----
    const int xbit = (lane >> 2) & 1;
    const int cg = lane & 3;
    const ushort* vh = vt + ((size_t)(b * 8 + h) * NV) * 32 + cg * 8;
    float acc[8] = {0.f, 0.f, 0.f, 0.f, 0.f, 0.f, 0.f, 0.f};

#pragma unroll
    for (int ss = 0; ss < 16; ++ss) {
        const int l2 = ss >> 2;
        const int Wi2 = (l2 == 0) ? 100 : (l2 == 1) ? 50 : (l2 == 2) ? 25 : 13;
        const int st2 = (l2 == 0) ? 0 : (l2 == 1) ? 10000 : (l2 == 2) ? 12500 : 13125;
        int4 ent = s_tbl[qi][h * 16 + (ss ^ h)];
        int x0 = (int)(short)(ent.x & 0xffff);
        int y0 = ent.x >> 16;
        float wx = xbit ? f16hi((uint)ent.y) : f16lo((uint)ent.y);
        float wy0 = f16lo((uint)ent.z), wy1 = f16hi((uint)ent.z);
        int px  = min(max(x0 + xbit, 0), Wi2 - 1);
        int py0 = min(max(y0, 0), Wi2 - 1);
        int py1 = min(max(y0 + 1, 0), Wi2 - 1);
        size_t p0 = (size_t)(st2 + py0 * Wi2 + px) * 32;
        size_t p1 = (size_t)(st2 + py1 * Wi2 + px) * 32;
        uint4 g0 = *reinterpret_cast<const uint4*>(vh + p0);
        uint4 g1 = *reinterpret_cast<const uint4*>(vh + p1);
        float w0 = wx * wy0, w1 = wx * wy1;
        acc[0] = fmaf(__uint_as_float(g0.x << 16), w0, acc[0]);
        acc[1] = fmaf(__uint_as_float(g0.x & 0xffff0000u), w0, acc[1]);
        acc[2] = fmaf(__uint_as_float(g0.y << 16), w0, acc[2]);
        acc[3] = fmaf(__uint_as_float(g0.y & 0xffff0000u), w0, acc[3]);
        acc[4] = fmaf(__uint_as_float(g0.z << 16), w0, acc[4]);
        acc[5] = fmaf(__uint_as_float(g0.z & 0xffff0000u), w0, acc[5]);
        acc[6] = fmaf(__uint_as_float(g0.w << 16), w0, acc[6]);
        acc[7] = fmaf(__uint_as_float(g0.w & 0xffff0000u), w0, acc[7]);
        acc[0] = fmaf(__uint_as_float(g1.x << 16), w1, acc[0]);
        acc[1] = fmaf(__uint_as_float(g1.x & 0xffff0000u), w1, acc[1]);
        acc[2] = fmaf(__uint_as_float(g1.y << 16), w1, acc[2]);
        acc[3] = fmaf(__uint_as_float(g1.y & 0xffff0000u), w1, acc[3]);
        acc[4] = fmaf(__uint_as_float(g1.z << 16), w1, acc[4]);
        acc[5] = fmaf(__uint_as_float(g1.z & 0xffff0000u), w1, acc[5]);
        acc[6] = fmaf(__uint_as_float(g1.w << 16), w1, acc[6]);
        acc[7] = fmaf(__uint_as_float(g1.w & 0xffff0000u), w1, acc[7]);
    }

#pragma unroll
    for (int i = 0; i < 8; ++i) acc[i] += __shfl_xor(acc[i], 4);   // sum x-corners
    if (xbit == 0) {
        uint4 o;
        o.x = cvtpk_bf16(acc[0], acc[1]);
        o.y = cvtpk_bf16(acc[2], acc[3]);
        o.z = cvtpk_bf16(acc[4], acc[5]);
        o.w = cvtpk_bf16(acc[6], acc[7]);
        *reinterpret_cast<uint4*>(out_acc + (size_t)bq * 256 + h * 32 + cg * 8) = o;
    }
}

// ---------- launch ----------
extern "C" void kernel_launch(void* const* d_in, const int* in_sizes, int n_in,
                              void* d_out, int out_size, void* d_ws, size_t ws_size,
                              hipStream_t stream) {
    const float* query  = (const float*)d_in[0];
    const float* value  = (const float*)d_in[1];
    const float* refp   = (const float*)d_in[2];
    const float* W_off  = (const float*)d_in[5];
    const float* b_off  = (const float*)d_in[6];
    const float* W_attn = (const float*)d_in[7];
    const float* b_attn = (const float*)d_in[8];
    const float* W_val  = (const float*)d_in[9];
    const float* b_val  = (const float*)d_in[10];
    const float* W_out  = (const float*)d_in[11];
    const float* b_out  = (const float*)d_in[12];

    const size_t ROWB = (size_t)BQ * 256 * 2;   // bytes of one bf16 [BQ,256] buffer
    char* ws = (char*)d_ws;
    ushort* vproj_t = (ushort*)(ws);                               // [B*8][NV][32] bf16
    ushort* outacc  = (ushort*)(ws + ROWB);                        // [BQ,256] bf16
    ushort* offattn = (ushort*)(ws + 2 * ROWB);                    // [BQ,384] fp16
    char*   wbase   = ws + 2 * ROWB + (size_t)BQ * 384 * 2;
    ushort* tWv  = (ushort*)(wbase);
    ushort* tWoa = tWv + 65536;
    ushort* tWu  = tWoa + 98304;
    float*  boa  = (float*)(tWu + 65536);

    prep_weights<<<(229760 + 255) / 256, 256, 0, stream>>>(
        W_val, W_off, W_attn, W_out, b_off, b_attn, tWv, tWoa, tWu, boa);

    gemm_fused<<<dim3(208, 5), 256, 0, stream>>>(
        value, query, tWv, tWoa, b_val, boa, vproj_t, offattn);

    msda_sample<<<BQ / 4, 256, 0, stream>>>(offattn, refp, vproj_t, outacc);

    gemm_out<<<dim3(208, 2), 256, 0, stream>>>(outacc, tWu, b_out, (float*)d_out);
}